// Round 7
// baseline (155.727 us; speedup 1.0000x reference)
//
#include <hip/hip_runtime.h>
#include <hip/hip_bf16.h>
#include <math.h>

typedef __attribute__((ext_vector_type(8))) short short8;
typedef __attribute__((ext_vector_type(4))) float f32x4;
typedef __attribute__((ext_vector_type(4))) float float4v;
typedef __attribute__((ext_vector_type(4))) unsigned short ushort4v;

typedef __attribute__((address_space(1))) const unsigned int GAS;
typedef __attribute__((address_space(3))) unsigned int LAS;

#define B_ 4
#define S_ 4096
#define D_ 128

// geometry: q-tile = 128 rows (8 waves x 16), kv-tile = 64 keys, chunk = 4 kv-tiles
// per batch: q-tile qt needs tiles 0..2qt+1; nc(qt) = qt/2 + 1; CPB = sum = 272
#define CPB 272
#define NSLOT (B_ * CPB)   // 1088 partial slots, 128 rows each

// LDS layout (bytes): K 16K single | V 2x16K dbuf | P 8 waves x 2K = 64KB exactly
#define LDS_K 0
#define LDS_V 16384
#define LDS_P 49152
#define LDS_TOTAL 65536

__device__ __forceinline__ unsigned short f2bf(float f) {
    union { float f; unsigned u; } v; v.f = f;
    unsigned r = v.u + 0x7FFFu + ((v.u >> 16) & 1u);
    return (unsigned short)(r >> 16);
}
__device__ __forceinline__ float bf2f(unsigned short h) {
    union { unsigned u; float f; } v; v.u = ((unsigned)h) << 16;
    return v.f;
}

// ---------------- kernel 0: W -> bf16, concat [Wq;Wk;Wv] as [384][128] ----------------
__global__ void wconv_kernel(const float* __restrict__ Wq,
                             const float* __restrict__ Wk,
                             const float* __restrict__ Wv,
                             unsigned short* __restrict__ Wb) {
    int i = blockIdx.x * 256 + threadIdx.x;
    if (i >= 3 * 16384) return;
    const float* s = (i < 16384) ? Wq : (i < 32768 ? Wk : Wv);
    Wb[i] = f2bf(s[i & 16383]);
}

// ---------------- kernel 1: QKV projection (scale folded into Q) ----------------
__global__ __launch_bounds__(256) void qkv_kernel(const float* __restrict__ X,
                                                  const unsigned short* __restrict__ Wb,
                                                  unsigned short* __restrict__ Qb,
                                                  unsigned short* __restrict__ Kb,
                                                  unsigned short* __restrict__ Vt) {
    const int tid = threadIdx.x;
    const int lane = tid & 63, w = tid >> 6;
    const int l16 = lane & 15, g = lane >> 4;
    const int r0 = blockIdx.x * 64;
    const int grp = blockIdx.y;

    const int row = r0 + w * 16 + l16;
    const float* xr = X + (long)row * 128;
    float4v x0[4], x1[4];
    #pragma unroll
    for (int kb = 0; kb < 4; ++kb) {
        x0[kb] = *reinterpret_cast<const float4v*>(xr + kb * 32 + g * 8);
        x1[kb] = *reinterpret_cast<const float4v*>(xr + kb * 32 + g * 8 + 4);
    }
    short8 a[4];
    #pragma unroll
    for (int kb = 0; kb < 4; ++kb) {
        short8 t;
        t[0] = f2bf(x0[kb][0]); t[1] = f2bf(x0[kb][1]);
        t[2] = f2bf(x0[kb][2]); t[3] = f2bf(x0[kb][3]);
        t[4] = f2bf(x1[kb][0]); t[5] = f2bf(x1[kb][1]);
        t[6] = f2bf(x1[kb][2]); t[7] = f2bf(x1[kb][3]);
        a[kb] = t;
    }

    const float scale = 0.08838834764831845f; // 1/sqrt(128)
    #pragma unroll
    for (int ct = 0; ct < 8; ++ct) {
        const int e = ct * 16 + l16;
        const int c = grp * 128 + e;
        f32x4 acc = {0.f, 0.f, 0.f, 0.f};
        #pragma unroll
        for (int kb = 0; kb < 4; ++kb) {
            short8 bf = *reinterpret_cast<const short8*>(Wb + (long)c * 128 + kb * 32 + g * 8);
            acc = __builtin_amdgcn_mfma_f32_16x16x32_bf16(a[kb], bf, acc, 0, 0, 0);
        }
        const int row0 = r0 + w * 16 + g * 4;
        if (grp == 0) {
            #pragma unroll
            for (int r = 0; r < 4; ++r) Qb[(long)(row0 + r) * 128 + e] = f2bf(acc[r] * scale);
        } else if (grp == 1) {
            #pragma unroll
            for (int r = 0; r < 4; ++r) Kb[(long)(row0 + r) * 128 + e] = f2bf(acc[r]);
        } else {
            const int bb = row0 >> 12, ss = row0 & 4095;
            ushort4v p;
            p[0] = f2bf(acc[0]); p[1] = f2bf(acc[1]); p[2] = f2bf(acc[2]); p[3] = f2bf(acc[3]);
            *reinterpret_cast<ushort4v*>(&Vt[((long)bb * 128 + e) * 4096 + ss]) = p;
        }
    }
}

// ---------------- kernel 2: split-KV flash attention, 8 waves / 128 q-rows ----------------
// Per iter: QK^T(K) -> barrier -> prefetch DMA (K, V[buf^1]) -> softmax -> PV(V[buf]) -> barrier.
// Prefetch drains at the end-of-iter barrier, hidden under softmax+PV.
__global__ __launch_bounds__(512) void attn_kernel(const unsigned short* __restrict__ Qb,
                                                   const unsigned short* __restrict__ Kb,
                                                   const unsigned short* __restrict__ Vt,
                                                   unsigned short* __restrict__ Opart,
                                                   float* __restrict__ Mpart,
                                                   float* __restrict__ Lpart) {
    __shared__ __align__(16) unsigned char lds[LDS_TOTAL];

    const int tid = threadIdx.x;
    const int lane = tid & 63, w = tid >> 6;          // w in 0..7
    const int l16 = lane & 15, g = lane >> 4;

    // block -> (b, qt, c): rr = S(qt) + c, S(2h)=h(h+1), S(2h+1)=(h+1)^2
    const int bidx = (int)blockIdx.x;
    const int b = bidx / CPB;
    const int rr = bidx - b * CPB;
    int h = 0;
    while ((h + 1) * (h + 2) <= rr) ++h;              // <= 15 iters
    int qt, c;
    {
        int rem = rr - h * (h + 1);
        if (rem < h + 1) { qt = 2 * h; c = rem; }
        else             { qt = 2 * h + 1; c = rr - (h + 1) * (h + 1); }
    }
    const int slot = bidx;

    const unsigned short* Qbase = Qb + (long)b * S_ * D_;
    const unsigned char* Kb_b = (const unsigned char*)(Kb + (long)b * S_ * D_);
    const unsigned char* Vb_b = (const unsigned char*)(Vt + (long)b * D_ * S_);

    // Q fragments (pre-scaled), rows qt*128 + w*16 + l16
    const int qrow_f = qt * 128 + w * 16 + l16;
    short8 qf[4];
    #pragma unroll
    for (int kb = 0; kb < 4; ++kb)
        qf[kb] = *reinterpret_cast<const short8*>(Qbase + (long)qrow_f * 128 + kb * 32 + g * 8);

    // pre-swizzled global source offsets for DMA (XOR involution, verified r4/r6)
    int koff[2], voff[2];
    #pragma unroll
    for (int it = 0; it < 2; ++it) {
        int krow = it * 32 + w * 4 + (lane >> 4);
        koff[it] = krow * 256 + ((l16 * 16) ^ ((krow & 7) << 4));
        int vrow = it * 64 + w * 8 + (lane >> 3);
        voff[it] = vrow * 8192 + (((lane & 7) * 16) ^ ((vrow & 7) << 4));
    }

    f32x4 o[8];
    #pragma unroll
    for (int dt = 0; dt < 8; ++dt) o[dt] = (f32x4){0.f, 0.f, 0.f, 0.f};
    float m[4], lsum[4];
    int myrow[4];
    #pragma unroll
    for (int r = 0; r < 4; ++r) {
        m[r] = -INFINITY; lsum[r] = 0.f;
        myrow[r] = qt * 128 + w * 16 + g * 4 + r;
    }

    const int kt0 = c * 4;
    const int ktend = min(kt0 + 3, 2 * qt + 1);

    unsigned char* Pw = lds + LDS_P + w * 2048;

    // prologue: DMA K and V[buf0] for kt0
    {
        const int buf0 = kt0 & 1;
        #pragma unroll
        for (int it = 0; it < 2; ++it) {
            __builtin_amdgcn_global_load_lds((GAS*)(Kb_b + (long)kt0 * 16384 + koff[it]),
                                             (LAS*)(lds + LDS_K + it * 8192 + w * 1024), 16, 0, 0);
            __builtin_amdgcn_global_load_lds((GAS*)(Vb_b + (long)kt0 * 128 + voff[it]),
                                             (LAS*)(lds + LDS_V + buf0 * 16384 + it * 8192 + w * 1024), 16, 0, 0);
        }
    }
    __syncthreads();

    for (int kt = kt0; kt <= ktend; ++kt) {
        const int buf = kt & 1;
        const bool more = (kt < ktend);

        // ---- S = Q K^T ----
        f32x4 s[4];
        __builtin_amdgcn_s_setprio(1);
        #pragma unroll
        for (int ct = 0; ct < 4; ++ct) {
            s[ct] = (f32x4){0.f, 0.f, 0.f, 0.f};
            const int kvl = ct * 16 + l16;
            #pragma unroll
            for (int kb = 0; kb < 4; ++kb) {
                int byt = (kvl * 256 + kb * 64 + g * 16) ^ ((kvl & 7) << 4);
                short8 kf = *reinterpret_cast<const short8*>(lds + byt);
                s[ct] = __builtin_amdgcn_mfma_f32_16x16x32_bf16(qf[kb], kf, s[ct], 0, 0, 0);
            }
        }
        __builtin_amdgcn_s_setprio(0);

        __syncthreads();   // all waves done reading K tile

        // prefetch next tile (drains at end-of-iter barrier, under softmax+PV)
        if (more) {
            #pragma unroll
            for (int it = 0; it < 2; ++it) {
                __builtin_amdgcn_global_load_lds((GAS*)(Kb_b + (long)(kt + 1) * 16384 + koff[it]),
                                                 (LAS*)(lds + LDS_K + it * 8192 + w * 1024), 16, 0, 0);
                __builtin_amdgcn_global_load_lds((GAS*)(Vb_b + (long)(kt + 1) * 128 + voff[it]),
                                                 (LAS*)(lds + LDS_V + (buf ^ 1) * 16384 + it * 8192 + w * 1024), 16, 0, 0);
            }
        }

        // ---- online softmax with defer-rescale (T13) ----
        const bool anymask = (kt * 64 + 63 > qt * 128 + w * 16);
        float rmax[4] = {-1e30f, -1e30f, -1e30f, -1e30f};
        #pragma unroll
        for (int ct = 0; ct < 4; ++ct) {
            #pragma unroll
            for (int r = 0; r < 4; ++r) {
                float sv = s[ct][r];
                if (anymask && (kt * 64 + ct * 16 + l16 > myrow[r])) sv = -1e30f;
                s[ct][r] = sv;
                rmax[r] = fmaxf(rmax[r], sv);
            }
        }
        #pragma unroll
        for (int off = 1; off < 16; off <<= 1) {
            #pragma unroll
            for (int r = 0; r < 4; ++r) rmax[r] = fmaxf(rmax[r], __shfl_xor(rmax[r], off, 64));
        }
        bool upd = false;
        #pragma unroll
        for (int r = 0; r < 4; ++r) upd = upd || (rmax[r] > m[r] + 8.0f);
        if (__any(upd)) {
            float al[4];
            #pragma unroll
            for (int r = 0; r < 4; ++r) {
                float mn = fmaxf(m[r], rmax[r]);
                al[r] = __expf(m[r] - mn);
                m[r] = mn;
                lsum[r] *= al[r];
            }
            #pragma unroll
            for (int dt = 0; dt < 8; ++dt) {
                #pragma unroll
                for (int r = 0; r < 4; ++r) o[dt][r] *= al[r];
            }
        }
        float rsum[4] = {0.f, 0.f, 0.f, 0.f};
        #pragma unroll
        for (int ct = 0; ct < 4; ++ct) {
            #pragma unroll
            for (int r = 0; r < 4; ++r) {
                float p = __expf(s[ct][r] - m[r]);
                s[ct][r] = p;
                rsum[r] += p;
            }
        }
        #pragma unroll
        for (int off = 1; off < 16; off <<= 1) {
            #pragma unroll
            for (int r = 0; r < 4; ++r) rsum[r] += __shfl_xor(rsum[r], off, 64);
        }
        #pragma unroll
        for (int r = 0; r < 4; ++r) lsum[r] += rsum[r];

        // ---- P -> per-wave LDS (swizzled; wave-private) ----
        #pragma unroll
        for (int ct = 0; ct < 4; ++ct) {
            #pragma unroll
            for (int r = 0; r < 4; ++r) {
                int pr = g * 4 + r, pc = ct * 16 + l16;
                int byt = (pr * 128 + pc * 2) ^ ((pr & 7) << 4);
                *reinterpret_cast<unsigned short*>(Pw + byt) = f2bf(s[ct][r]);
            }
        }

        // ---- O += P V ----
        #pragma unroll
        for (int kvb = 0; kvb < 2; ++kvb) {
            int pbyt = (l16 * 128 + kvb * 64 + g * 16) ^ ((l16 & 7) << 4);
            short8 pf = *reinterpret_cast<const short8*>(Pw + pbyt);
            __builtin_amdgcn_s_setprio(1);
            #pragma unroll
            for (int dt = 0; dt < 8; ++dt) {
                int d = dt * 16 + l16;
                int vbyt = LDS_V + buf * 16384 + ((d * 128 + kvb * 64 + g * 16) ^ ((d & 7) << 4));
                short8 vf = *reinterpret_cast<const short8*>(lds + vbyt);
                o[dt] = __builtin_amdgcn_mfma_f32_16x16x32_bf16(pf, vf, o[dt], 0, 0, 0);
            }
            __builtin_amdgcn_s_setprio(0);
        }

        if (more) __syncthreads();   // drains prefetch DMA; releases K and V[buf]
    }

    // ---- partial epilogue: unnormalized O (bf16) + m,l (f32), 128-row slot ----
    unsigned short* Op = Opart + (long)slot * 16384;
    #pragma unroll
    for (int dt = 0; dt < 8; ++dt) {
        #pragma unroll
        for (int r = 0; r < 4; ++r) {
            Op[(w * 16 + g * 4 + r) * 128 + dt * 16 + l16] = f2bf(o[dt][r]);
        }
    }
    if (l16 == 0) {
        #pragma unroll
        for (int r = 0; r < 4; ++r) {
            Mpart[(long)slot * 128 + w * 16 + g * 4 + r] = m[r];
            Lpart[(long)slot * 128 + w * 16 + g * 4 + r] = lsum[r];
        }
    }
}

// ---------------- kernel 3: combine partials ----------------
// grid (256, 4): x = qt*8 + eighth, y = b. Each block merges 16 rows of a 128-row q-tile.
__global__ __launch_bounds__(256) void combine_kernel(const unsigned short* __restrict__ Opart,
                                                      const float* __restrict__ Mpart,
                                                      const float* __restrict__ Lpart,
                                                      float* __restrict__ out) {
    __shared__ float coeff[16][16];
    __shared__ float invL[16];

    const int qt = blockIdx.x >> 3, qq = blockIdx.x & 7, b = blockIdx.y;
    const int h = qt >> 1;
    const int nc = h + 1;
    const int sbase = (qt & 1) ? (h + 1) * (h + 1) : h * (h + 1);
    const int slot0 = b * CPB + sbase;
    const int r0 = qq * 16;

    const int tid = threadIdx.x;
    if (tid < 16) {
        float mg = -INFINITY;
        for (int c = 0; c < nc; ++c)
            mg = fmaxf(mg, Mpart[(long)(slot0 + c) * 128 + r0 + tid]);
        float L = 0.f;
        for (int c = 0; c < nc; ++c) {
            float co = __expf(Mpart[(long)(slot0 + c) * 128 + r0 + tid] - mg);
            coeff[c][tid] = co;
            L += co * Lpart[(long)(slot0 + c) * 128 + r0 + tid];
        }
        invL[tid] = 1.f / L;
    }
    __syncthreads();

    const int e0 = tid * 8;
    const int r = e0 >> 7;
    float acc[8];
    #pragma unroll
    for (int k = 0; k < 8; ++k) acc[k] = 0.f;
    for (int c = 0; c < nc; ++c) {
        short8 v = *reinterpret_cast<const short8*>(Opart + (long)(slot0 + c) * 16384 + r0 * 128 + e0);
        const float co = coeff[c][r];
        #pragma unroll
        for (int k = 0; k < 8; ++k)
            acc[k] += co * bf2f((unsigned short)v[k]);
    }
    const float s = invL[r];
    float4v o0, o1;
    o0[0] = acc[0] * s; o0[1] = acc[1] * s; o0[2] = acc[2] * s; o0[3] = acc[3] * s;
    o1[0] = acc[4] * s; o1[1] = acc[5] * s; o1[2] = acc[6] * s; o1[3] = acc[7] * s;
    float* dst = out + ((long)b * S_ + qt * 128 + r0) * 128 + e0;
    *reinterpret_cast<float4v*>(dst) = o0;
    *reinterpret_cast<float4v*>(dst + 4) = o1;
}

extern "C" void kernel_launch(void* const* d_in, const int* in_sizes, int n_in,
                              void* d_out, int out_size, void* d_ws, size_t ws_size,
                              hipStream_t stream) {
    (void)in_sizes; (void)n_in; (void)out_size; (void)ws_size;
    const float* x  = (const float*)d_in[0];
    const float* Wq = (const float*)d_in[1];
    const float* Wk = (const float*)d_in[2];
    const float* Wv = (const float*)d_in[3];
    float* out = (float*)d_out;

    char* ws = (char*)d_ws;
    const size_t MB4 = (size_t)16384 * 128 * 2;         // 4 MiB per bf16 tensor
    unsigned short* Qb = (unsigned short*)(ws);
    unsigned short* Kb = (unsigned short*)(ws + MB4);
    unsigned short* Vt = (unsigned short*)(ws + 2 * MB4);
    unsigned short* Wb = (unsigned short*)(ws + 3 * MB4);          // 96 KiB
    unsigned short* Opart = (unsigned short*)(ws + 3 * MB4 + (1 << 20));   // 1088*32KiB = 34.8 MiB
    float* Mpart = (float*)(ws + 3 * MB4 + (1 << 20) + (size_t)NSLOT * 16384 * 2);
    float* Lpart = Mpart + (size_t)NSLOT * 128;

    wconv_kernel<<<192, 256, 0, stream>>>(Wq, Wk, Wv, Wb);
    qkv_kernel<<<dim3(256, 3), 256, 0, stream>>>(x, Wb, Qb, Kb, Vt);
    attn_kernel<<<NSLOT, 512, 0, stream>>>(Qb, Kb, Vt, Opart, Mpart, Lpart);
    combine_kernel<<<dim3(256, 4), 256, 0, stream>>>(Opart, Mpart, Lpart, out);
}

// Round 8
// 141.422 us; speedup vs baseline: 1.1012x; 1.1012x over previous
//
#include <hip/hip_runtime.h>
#include <hip/hip_bf16.h>
#include <math.h>

typedef __attribute__((ext_vector_type(8))) short short8;
typedef __attribute__((ext_vector_type(4))) float f32x4;
typedef __attribute__((ext_vector_type(4))) float float4v;
typedef __attribute__((ext_vector_type(4))) unsigned short ushort4v;

typedef __attribute__((address_space(1))) const unsigned int GAS;
typedef __attribute__((address_space(3))) unsigned int LAS;

#define B_ 4
#define S_ 4096
#define D_ 128

// split-KV geometry: q-tile = 64 rows, kv-tile = 64 keys, chunk = 4 kv-tiles
#define CPB 544
#define NSLOT (B_ * CPB)   // 2176 partial slots

// LDS layout (bytes): K 16K | V 16K | P 4 waves x 2K  => 40KB, 4 blocks/CU
#define LDS_K 0
#define LDS_V 16384
#define LDS_P 32768
#define LDS_TOTAL 40960

__device__ __forceinline__ unsigned short f2bf(float f) {
    union { float f; unsigned u; } v; v.f = f;
    unsigned r = v.u + 0x7FFFu + ((v.u >> 16) & 1u);
    return (unsigned short)(r >> 16);
}
__device__ __forceinline__ float bf2f(unsigned short h) {
    union { unsigned u; float f; } v; v.u = ((unsigned)h) << 16;
    return v.f;
}

// ---------------- kernel 0: W -> bf16, concat [Wq;Wk;Wv] as [384][128] ----------------
__global__ void wconv_kernel(const float* __restrict__ Wq,
                             const float* __restrict__ Wk,
                             const float* __restrict__ Wv,
                             unsigned short* __restrict__ Wb) {
    int i = blockIdx.x * 256 + threadIdx.x;
    if (i >= 3 * 16384) return;
    const float* s = (i < 16384) ? Wq : (i < 32768 ? Wk : Wv);
    Wb[i] = f2bf(s[i & 16383]);
}

// ---------------- kernel 1: QKV projection (1/sqrt(D) folded into Q) ----------------
__global__ __launch_bounds__(256) void qkv_kernel(const float* __restrict__ X,
                                                  const unsigned short* __restrict__ Wb,
                                                  unsigned short* __restrict__ Qb,
                                                  unsigned short* __restrict__ Kb,
                                                  unsigned short* __restrict__ Vt) {
    const int tid = threadIdx.x;
    const int lane = tid & 63, w = tid >> 6;
    const int l16 = lane & 15, g = lane >> 4;
    const int r0 = blockIdx.x * 64;
    const int grp = blockIdx.y;

    const int row = r0 + w * 16 + l16;
    const float* xr = X + (long)row * 128;
    float4v x0[4], x1[4];
    #pragma unroll
    for (int kb = 0; kb < 4; ++kb) {
        x0[kb] = *reinterpret_cast<const float4v*>(xr + kb * 32 + g * 8);
        x1[kb] = *reinterpret_cast<const float4v*>(xr + kb * 32 + g * 8 + 4);
    }
    short8 a[4];
    #pragma unroll
    for (int kb = 0; kb < 4; ++kb) {
        short8 t;
        t[0] = f2bf(x0[kb][0]); t[1] = f2bf(x0[kb][1]);
        t[2] = f2bf(x0[kb][2]); t[3] = f2bf(x0[kb][3]);
        t[4] = f2bf(x1[kb][0]); t[5] = f2bf(x1[kb][1]);
        t[6] = f2bf(x1[kb][2]); t[7] = f2bf(x1[kb][3]);
        a[kb] = t;
    }

    const float scale = 0.08838834764831845f; // 1/sqrt(128)
    #pragma unroll
    for (int ct = 0; ct < 8; ++ct) {
        const int e = ct * 16 + l16;
        const int c = grp * 128 + e;
        f32x4 acc = {0.f, 0.f, 0.f, 0.f};
        #pragma unroll
        for (int kb = 0; kb < 4; ++kb) {
            short8 bf = *reinterpret_cast<const short8*>(Wb + (long)c * 128 + kb * 32 + g * 8);
            acc = __builtin_amdgcn_mfma_f32_16x16x32_bf16(a[kb], bf, acc, 0, 0, 0);
        }
        const int row0 = r0 + w * 16 + g * 4;
        if (grp == 0) {
            #pragma unroll
            for (int r = 0; r < 4; ++r) Qb[(long)(row0 + r) * 128 + e] = f2bf(acc[r] * scale);
        } else if (grp == 1) {
            #pragma unroll
            for (int r = 0; r < 4; ++r) Kb[(long)(row0 + r) * 128 + e] = f2bf(acc[r]);
        } else {
            const int bb = row0 >> 12, ss = row0 & 4095;
            ushort4v p;
            p[0] = f2bf(acc[0]); p[1] = f2bf(acc[1]); p[2] = f2bf(acc[2]); p[3] = f2bf(acc[3]);
            *reinterpret_cast<ushort4v*>(&Vt[((long)bb * 128 + e) * 4096 + ss]) = p;
        }
    }
}

// ---------------- kernel 2: split-KV flash attention, VALU-dieted ----------------
// r6 structure: per iter DMA K/V -> barrier -> QK^T -> softmax -> PV -> barrier.
// All LDS read addresses hoisted to loop-invariant registers + imm offsets:
//   K read  = kaddr[kb] + ct*4096 ; V read = vaddr[kvb] + dt*2048 ; P read = pread[kvb]
// Masking applied only on the diagonal tile (wave-uniform branch).
__global__ __launch_bounds__(256, 4) void attn_kernel(const unsigned short* __restrict__ Qb,
                                                      const unsigned short* __restrict__ Kb,
                                                      const unsigned short* __restrict__ Vt,
                                                      unsigned short* __restrict__ Opart,
                                                      float* __restrict__ Mpart,
                                                      float* __restrict__ Lpart) {
    __shared__ __align__(16) unsigned char lds[LDS_TOTAL];

    const int tid = threadIdx.x;
    const int lane = tid & 63, w = tid >> 6;
    const int l16 = lane & 15, g = lane >> 4;

    // block -> (b, qt, c); reversed so longest blocks dispatch first
    const int bidx = (int)blockIdx.x;
    const int b = bidx / CPB;
    const int rr = CPB - 1 - (bidx - b * CPB);
    int gg = 0;
    while (2 * (gg + 1) * (gg + 2) <= rr) ++gg;      // <= 15 iters
    const int j = rr - 2 * gg * (gg + 1);
    const int qt = 4 * gg + j / (gg + 1);
    const int c = j % (gg + 1);
    const int slot = b * CPB + rr;

    const unsigned short* Qbase = Qb + (long)b * S_ * D_;
    const unsigned char* Kb_b = (const unsigned char*)(Kb + (long)b * S_ * D_);
    const unsigned char* Vb_b = (const unsigned char*)(Vt + (long)b * D_ * S_);

    // Q fragments (pre-scaled by 1/sqrt(D))
    const int qrow_f = qt * 64 + w * 16 + l16;
    short8 qf[4];
    #pragma unroll
    for (int kb = 0; kb < 4; ++kb)
        qf[kb] = *reinterpret_cast<const short8*>(Qbase + (long)qrow_f * 128 + kb * 32 + g * 8);

    // pre-swizzled global source offsets for DMA staging (XOR involution, verified r4/r6)
    int koff[4], voff[4];
    #pragma unroll
    for (int i = 0; i < 4; ++i) {
        int ch = i * 256 + tid;
        int krow = ch >> 4, kcd = ch & 15;
        koff[i] = krow * 256 + ((kcd * 16) ^ ((krow & 7) << 4));
        int vrow = ch >> 3, vck = ch & 7;
        voff[i] = vrow * 8192 + ((vck * 16) ^ ((vrow & 7) << 4));
    }

    // hoisted swizzled LDS read bases (loop-invariant; imm offsets at use sites)
    const int swz = (l16 & 7) << 4;
    const unsigned char* kaddr[4];
    const unsigned char* vaddr[2];
    const unsigned char* pread[2];
    unsigned char* Pw = lds + LDS_P + w * 2048;
    #pragma unroll
    for (int i = 0; i < 4; ++i)
        kaddr[i] = lds + LDS_K + l16 * 256 + ((i * 64 + g * 16) ^ swz);
    #pragma unroll
    for (int i = 0; i < 2; ++i) {
        const int xo = (i * 64 + g * 16) ^ swz;
        vaddr[i] = lds + LDS_V + l16 * 128 + xo;
        pread[i] = Pw + l16 * 128 + xo;
    }
    // P write: addr = prow[r] + ((ct*32 + l16*2) ^ pmask[r])
    unsigned char* prow[4];
    int pmask[4];
    #pragma unroll
    for (int r = 0; r < 4; ++r) {
        const int pr = g * 4 + r;
        prow[r] = Pw + pr * 128;
        pmask[r] = (pr & 7) << 4;
    }
    const int pl2 = l16 * 2;

    f32x4 o[8];
    #pragma unroll
    for (int dt = 0; dt < 8; ++dt) o[dt] = (f32x4){0.f, 0.f, 0.f, 0.f};
    float m[4], lsum[4];
    int myrow[4];
    #pragma unroll
    for (int r = 0; r < 4; ++r) {
        m[r] = -INFINITY; lsum[r] = 0.f;
        myrow[r] = qt * 64 + w * 16 + g * 4 + r;
    }

    const int kt0 = c * 4;
    const int ktend = min(kt0 + 3, qt);

    for (int kt = kt0; kt <= ktend; ++kt) {
        // ---- DMA this tile's K and V into LDS ----
        #pragma unroll
        for (int i = 0; i < 4; ++i) {
            int ch = i * 256 + tid;
            __builtin_amdgcn_global_load_lds((GAS*)(Kb_b + (long)kt * 16384 + koff[i]),
                                             (LAS*)(lds + LDS_K + ch * 16), 16, 0, 0);
            __builtin_amdgcn_global_load_lds((GAS*)(Vb_b + (long)kt * 128 + voff[i]),
                                             (LAS*)(lds + LDS_V + ch * 16), 16, 0, 0);
        }
        __syncthreads();   // vmcnt(0) drain + barrier: tile resident

        // ---- S = Q K^T ----
        f32x4 s[4];
        __builtin_amdgcn_s_setprio(1);
        #pragma unroll
        for (int ct = 0; ct < 4; ++ct) {
            s[ct] = (f32x4){0.f, 0.f, 0.f, 0.f};
            #pragma unroll
            for (int kb = 0; kb < 4; ++kb) {
                short8 kf = *reinterpret_cast<const short8*>(kaddr[kb] + ct * 4096);
                s[ct] = __builtin_amdgcn_mfma_f32_16x16x32_bf16(qf[kb], kf, s[ct], 0, 0, 0);
            }
        }
        __builtin_amdgcn_s_setprio(0);

        // ---- causal mask: only the diagonal tile needs it (wave-uniform branch) ----
        if (kt == qt) {
            #pragma unroll
            for (int ct = 0; ct < 4; ++ct) {
                const int col = kt * 64 + ct * 16 + l16;
                #pragma unroll
                for (int r = 0; r < 4; ++r)
                    if (col > myrow[r]) s[ct][r] = -1e30f;
            }
        }

        // ---- online softmax with defer-rescale (T13) ----
        float rmax[4];
        #pragma unroll
        for (int r = 0; r < 4; ++r)
            rmax[r] = fmaxf(fmaxf(s[0][r], s[1][r]), fmaxf(s[2][r], s[3][r]));
        #pragma unroll
        for (int off = 1; off < 16; off <<= 1) {
            #pragma unroll
            for (int r = 0; r < 4; ++r) rmax[r] = fmaxf(rmax[r], __shfl_xor(rmax[r], off, 64));
        }
        bool upd = false;
        #pragma unroll
        for (int r = 0; r < 4; ++r) upd = upd || (rmax[r] > m[r] + 8.0f);
        if (__any(upd)) {
            float al[4];
            #pragma unroll
            for (int r = 0; r < 4; ++r) {
                float mn = fmaxf(m[r], rmax[r]);
                al[r] = __expf(m[r] - mn);
                m[r] = mn;
                lsum[r] *= al[r];
            }
            #pragma unroll
            for (int dt = 0; dt < 8; ++dt) {
                #pragma unroll
                for (int r = 0; r < 4; ++r) o[dt][r] *= al[r];
            }
        }
        float rsum[4] = {0.f, 0.f, 0.f, 0.f};
        #pragma unroll
        for (int ct = 0; ct < 4; ++ct) {
            #pragma unroll
            for (int r = 0; r < 4; ++r) {
                float p = __expf(s[ct][r] - m[r]);
                s[ct][r] = p;
                rsum[r] += p;
            }
        }
        #pragma unroll
        for (int off = 1; off < 16; off <<= 1) {
            #pragma unroll
            for (int r = 0; r < 4; ++r) rsum[r] += __shfl_xor(rsum[r], off, 64);
        }
        #pragma unroll
        for (int r = 0; r < 4; ++r) lsum[r] += rsum[r];

        // ---- P -> per-wave LDS (swizzled; wave-private) ----
        #pragma unroll
        for (int ct = 0; ct < 4; ++ct) {
            #pragma unroll
            for (int r = 0; r < 4; ++r) {
                *reinterpret_cast<unsigned short*>(prow[r] + ((ct * 32 + pl2) ^ pmask[r])) =
                    f2bf(s[ct][r]);
            }
        }

        // ---- O += P V ----
        #pragma unroll
        for (int kvb = 0; kvb < 2; ++kvb) {
            short8 pf = *reinterpret_cast<const short8*>(pread[kvb]);
            __builtin_amdgcn_s_setprio(1);
            #pragma unroll
            for (int dt = 0; dt < 8; ++dt) {
                short8 vf = *reinterpret_cast<const short8*>(vaddr[kvb] + dt * 2048);
                o[dt] = __builtin_amdgcn_mfma_f32_16x16x32_bf16(pf, vf, o[dt], 0, 0, 0);
            }
            __builtin_amdgcn_s_setprio(0);
        }

        if (kt < ktend) __syncthreads();   // all waves done with tile before next DMA
    }

    // ---- partial epilogue: unnormalized O (bf16) + m,l (f32) ----
    unsigned short* Op = Opart + (long)slot * 8192;
    #pragma unroll
    for (int dt = 0; dt < 8; ++dt) {
        #pragma unroll
        for (int r = 0; r < 4; ++r) {
            Op[(w * 16 + g * 4 + r) * 128 + dt * 16 + l16] = f2bf(o[dt][r]);
        }
    }
    if (l16 == 0) {
        #pragma unroll
        for (int r = 0; r < 4; ++r) {
            Mpart[(long)slot * 64 + w * 16 + g * 4 + r] = m[r];
            Lpart[(long)slot * 64 + w * 16 + g * 4 + r] = lsum[r];
        }
    }
}

// ---------------- kernel 3: combine partials ----------------
// grid (256, 4): x = qt*4 + quarter, y = b. Each block merges 16 rows of one q-tile.
__global__ __launch_bounds__(256) void combine_kernel(const unsigned short* __restrict__ Opart,
                                                      const float* __restrict__ Mpart,
                                                      const float* __restrict__ Lpart,
                                                      float* __restrict__ out) {
    __shared__ float coeff[16][16];
    __shared__ float invL[16];

    const int qt = blockIdx.x >> 2, qq = blockIdx.x & 3, b = blockIdx.y;
    const int gg = qt >> 2;
    const int nc = gg + 1;
    const int slot0 = b * CPB + 2 * gg * (gg + 1) + (qt - 4 * gg) * nc;
    const int r0 = qq * 16;

    const int tid = threadIdx.x;
    if (tid < 16) {
        float mg = -INFINITY;
        for (int c = 0; c < nc; ++c)
            mg = fmaxf(mg, Mpart[(long)(slot0 + c) * 64 + r0 + tid]);
        float L = 0.f;
        for (int c = 0; c < nc; ++c) {
            float co = __expf(Mpart[(long)(slot0 + c) * 64 + r0 + tid] - mg);
            coeff[c][tid] = co;
            L += co * Lpart[(long)(slot0 + c) * 64 + r0 + tid];
        }
        invL[tid] = 1.f / L;
    }
    __syncthreads();

    const int e0 = tid * 8;
    const int r = e0 >> 7;
    float acc[8];
    #pragma unroll
    for (int k = 0; k < 8; ++k) acc[k] = 0.f;
    for (int c = 0; c < nc; ++c) {
        short8 v = *reinterpret_cast<const short8*>(Opart + (long)(slot0 + c) * 8192 + r0 * 128 + e0);
        const float co = coeff[c][r];
        #pragma unroll
        for (int k = 0; k < 8; ++k)
            acc[k] += co * bf2f((unsigned short)v[k]);
    }
    const float s = invL[r];
    float4v o0, o1;
    o0[0] = acc[0] * s; o0[1] = acc[1] * s; o0[2] = acc[2] * s; o0[3] = acc[3] * s;
    o1[0] = acc[4] * s; o1[1] = acc[5] * s; o1[2] = acc[6] * s; o1[3] = acc[7] * s;
    float* dst = out + ((long)b * S_ + qt * 64 + r0) * 128 + e0;
    *reinterpret_cast<float4v*>(dst) = o0;
    *reinterpret_cast<float4v*>(dst + 4) = o1;
}

extern "C" void kernel_launch(void* const* d_in, const int* in_sizes, int n_in,
                              void* d_out, int out_size, void* d_ws, size_t ws_size,
                              hipStream_t stream) {
    (void)in_sizes; (void)n_in; (void)out_size; (void)ws_size;
    const float* x  = (const float*)d_in[0];
    const float* Wq = (const float*)d_in[1];
    const float* Wk = (const float*)d_in[2];
    const float* Wv = (const float*)d_in[3];
    float* out = (float*)d_out;

    char* ws = (char*)d_ws;
    const size_t MB4 = (size_t)16384 * 128 * 2;         // 4 MiB per bf16 tensor
    unsigned short* Qb = (unsigned short*)(ws);
    unsigned short* Kb = (unsigned short*)(ws + MB4);
    unsigned short* Vt = (unsigned short*)(ws + 2 * MB4);
    unsigned short* Wb = (unsigned short*)(ws + 3 * MB4);          // 96 KiB
    unsigned short* Opart = (unsigned short*)(ws + 3 * MB4 + (1 << 20));   // 2176*16KiB
    float* Mpart = (float*)(ws + 3 * MB4 + (1 << 20) + (size_t)NSLOT * 8192 * 2);
    float* Lpart = Mpart + (size_t)NSLOT * 64;

    wconv_kernel<<<192, 256, 0, stream>>>(Wq, Wk, Wv, Wb);
    qkv_kernel<<<dim3(256, 3), 256, 0, stream>>>(x, Wb, Qb, Kb, Vt);
    attn_kernel<<<NSLOT, 256, 0, stream>>>(Qb, Kb, Vt, Opart, Mpart, Lpart);
    combine_kernel<<<dim3(256, 4), 256, 0, stream>>>(Opart, Mpart, Lpart, out);
}

// Round 10
// 128.037 us; speedup vs baseline: 1.2163x; 1.1045x over previous
//
#include <hip/hip_runtime.h>
#include <hip/hip_bf16.h>
#include <math.h>

typedef __attribute__((ext_vector_type(8))) short short8;
typedef __attribute__((ext_vector_type(2))) unsigned int uint2v;
typedef __attribute__((ext_vector_type(4))) float f32x4;
typedef __attribute__((ext_vector_type(4))) float float4v;
typedef __attribute__((ext_vector_type(4))) unsigned short ushort4v;

typedef __attribute__((address_space(1))) const unsigned int GAS;
typedef __attribute__((address_space(3))) unsigned int LAS;

#define B_ 4
#define S_ 4096
#define D_ 128

// split-KV geometry: q-tile = 64 rows, kv-tile = 64 keys, chunk = 4 kv-tiles
#define CPB 544
#define NSLOT (B_ * CPB)   // 2176 partial slots

// LDS layout (bytes): K 16K | V 16K | P 4 waves x 2K => 40KB
#define LDS_K 0
#define LDS_V 16384
#define LDS_P 32768
#define LDS_TOTAL 40960

__device__ __forceinline__ unsigned short f2bf(float f) {
    union { float f; unsigned u; } v; v.f = f;
    unsigned r = v.u + 0x7FFFu + ((v.u >> 16) & 1u);
    return (unsigned short)(r >> 16);
}
__device__ __forceinline__ float bf2f(unsigned short h) {
    union { unsigned u; float f; } v; v.u = ((unsigned)h) << 16;
    return v.f;
}
__device__ __forceinline__ unsigned cvt_pk_bf16(float lo, float hi) {
    unsigned r;
    asm("v_cvt_pk_bf16_f32 %0, %1, %2" : "=v"(r) : "v"(lo), "v"(hi));
    return r;
}

// ---------------- kernel 0: W -> bf16, concat [Wq;Wk;Wv] as [384][128] ----------------
__global__ void wconv_kernel(const float* __restrict__ Wq,
                             const float* __restrict__ Wk,
                             const float* __restrict__ Wv,
                             unsigned short* __restrict__ Wb) {
    int i = blockIdx.x * 256 + threadIdx.x;
    if (i >= 3 * 16384) return;
    const float* s = (i < 16384) ? Wq : (i < 32768 ? Wk : Wv);
    Wb[i] = f2bf(s[i & 16383]);
}

// ---------------- kernel 1: QKV projection (log2e/sqrt(D) folded into Q) ----------------
__global__ __launch_bounds__(256) void qkv_kernel(const float* __restrict__ X,
                                                  const unsigned short* __restrict__ Wb,
                                                  unsigned short* __restrict__ Qb,
                                                  unsigned short* __restrict__ Kb,
                                                  unsigned short* __restrict__ Vt) {
    const int tid = threadIdx.x;
    const int lane = tid & 63, w = tid >> 6;
    const int l16 = lane & 15, g = lane >> 4;
    const int r0 = blockIdx.x * 64;
    const int grp = blockIdx.y;

    const int row = r0 + w * 16 + l16;
    const float* xr = X + (long)row * 128;
    float4v x0[4], x1[4];
    #pragma unroll
    for (int kb = 0; kb < 4; ++kb) {
        x0[kb] = *reinterpret_cast<const float4v*>(xr + kb * 32 + g * 8);
        x1[kb] = *reinterpret_cast<const float4v*>(xr + kb * 32 + g * 8 + 4);
    }
    short8 a[4];
    #pragma unroll
    for (int kb = 0; kb < 4; ++kb) {
        short8 t;
        t[0] = f2bf(x0[kb][0]); t[1] = f2bf(x0[kb][1]);
        t[2] = f2bf(x0[kb][2]); t[3] = f2bf(x0[kb][3]);
        t[4] = f2bf(x1[kb][0]); t[5] = f2bf(x1[kb][1]);
        t[6] = f2bf(x1[kb][2]); t[7] = f2bf(x1[kb][3]);
        a[kb] = t;
    }

    const float scale = 0.12751744416006513f; // log2(e)/sqrt(128): scores in log2 domain
    #pragma unroll
    for (int ct = 0; ct < 8; ++ct) {
        const int e = ct * 16 + l16;
        const int c = grp * 128 + e;
        f32x4 acc = {0.f, 0.f, 0.f, 0.f};
        #pragma unroll
        for (int kb = 0; kb < 4; ++kb) {
            short8 bf = *reinterpret_cast<const short8*>(Wb + (long)c * 128 + kb * 32 + g * 8);
            acc = __builtin_amdgcn_mfma_f32_16x16x32_bf16(a[kb], bf, acc, 0, 0, 0);
        }
        const int row0 = r0 + w * 16 + g * 4;
        if (grp == 0) {
            #pragma unroll
            for (int r = 0; r < 4; ++r) Qb[(long)(row0 + r) * 128 + e] = f2bf(acc[r] * scale);
        } else if (grp == 1) {
            #pragma unroll
            for (int r = 0; r < 4; ++r) Kb[(long)(row0 + r) * 128 + e] = f2bf(acc[r]);
        } else {
            const int bb = row0 >> 12, ss = row0 & 4095;
            ushort4v p;
            p[0] = f2bf(acc[0]); p[1] = f2bf(acc[1]); p[2] = f2bf(acc[2]); p[3] = f2bf(acc[3]);
            *reinterpret_cast<ushort4v*>(&Vt[((long)bb * 128 + e) * 4096 + ss]) = p;
        }
    }
}

// ---------------- kernel 2: split-KV flash attention ----------------
// Swapped QK^T: S^T = mfma(K, Q) -> lane owns ONE q-row (col=l16); row reduce = 15 ops + 2 shfl.
// P packed via cvt_pk -> 4 ds_write_b64 to swizzled per-wave P buffer -> proven r8 16x16x32 PV.
__global__ __launch_bounds__(256, 4) void attn_kernel(const unsigned short* __restrict__ Qb,
                                                      const unsigned short* __restrict__ Kb,
                                                      const unsigned short* __restrict__ Vt,
                                                      unsigned short* __restrict__ Opart,
                                                      float* __restrict__ Mpart,
                                                      float* __restrict__ Lpart) {
    __shared__ __align__(16) unsigned char lds[LDS_TOTAL];

    const int tid = threadIdx.x;
    const int lane = tid & 63, w = tid >> 6;
    const int l16 = lane & 15, g = lane >> 4;

    // block -> (b, qt, c); reversed so longest blocks dispatch first
    const int bidx = (int)blockIdx.x;
    const int b = bidx / CPB;
    const int rr = CPB - 1 - (bidx - b * CPB);
    int gg = 0;
    while (2 * (gg + 1) * (gg + 2) <= rr) ++gg;      // <= 15 iters
    const int j = rr - 2 * gg * (gg + 1);
    const int qt = 4 * gg + j / (gg + 1);
    const int c = j % (gg + 1);
    const int slot = b * CPB + rr;

    const unsigned short* Qbase = Qb + (long)b * S_ * D_;
    const unsigned char* Kb_b = (const unsigned char*)(Kb + (long)b * S_ * D_);
    const unsigned char* Vb_b = (const unsigned char*)(Vt + (long)b * D_ * S_);

    // Q fragments (pre-scaled; B-operand: col = l16 = this lane's q-row)
    const int qrow_f = qt * 64 + w * 16 + l16;
    short8 qf[4];
    #pragma unroll
    for (int kb = 0; kb < 4; ++kb)
        qf[kb] = *reinterpret_cast<const short8*>(Qbase + (long)qrow_f * 128 + kb * 32 + g * 8);

    // pre-swizzled global source offsets for DMA staging (XOR involution, verified r4/r6/r8)
    int koff[4], voff[4];
    #pragma unroll
    for (int i = 0; i < 4; ++i) {
        int ch = i * 256 + tid;
        int krow = ch >> 4, kcd = ch & 15;
        koff[i] = krow * 256 + ((kcd * 16) ^ ((krow & 7) << 4));
        int vrow = ch >> 3, vck = ch & 7;
        voff[i] = vrow * 8192 + ((vck * 16) ^ ((vrow & 7) << 4));
    }

    // hoisted swizzled LDS addresses (loop-invariant; imm offsets at use sites)
    const int swz = (l16 & 7) << 4;
    const unsigned char* kaddr[4];   // K A-frag: row = ct*16+l16, d-bytes kb*64+g*16; +ct*4096 imm
    const unsigned char* vaddr[2];   // V B-frag: d-row = dt*16+l16, k-bytes kvb*64+g*16; +dt*2048 imm
    const unsigned char* pread[2];   // P A-frag: q-row l16, k-bytes kvb*64+g*16
    unsigned char* pwrite[4];        // P write: q-row l16, k-bytes ct*32+g*8 (8B, cvt_pk pair)
    unsigned char* Pw = lds + LDS_P + w * 2048;
    #pragma unroll
    for (int i = 0; i < 4; ++i) {
        kaddr[i] = lds + LDS_K + l16 * 256 + ((i * 64 + g * 16) ^ swz);
        pwrite[i] = Pw + l16 * 128 + ((i * 32 + g * 8) ^ swz);
    }
    #pragma unroll
    for (int i = 0; i < 2; ++i) {
        const int xo = (i * 64 + g * 16) ^ swz;
        vaddr[i] = lds + LDS_V + l16 * 128 + xo;
        pread[i] = Pw + l16 * 128 + xo;
    }

    f32x4 o[8];
    #pragma unroll
    for (int dt = 0; dt < 8; ++dt) o[dt] = (f32x4){0.f, 0.f, 0.f, 0.f};
    float m = -INFINITY, lsum = 0.f;
    const int myq = qt * 64 + w * 16 + l16;   // this lane's q-row

    const int kt0 = c * 4;
    const int ktend = min(kt0 + 3, qt);

    for (int kt = kt0; kt <= ktend; ++kt) {
        // ---- DMA this tile's K and V into LDS ----
        #pragma unroll
        for (int i = 0; i < 4; ++i) {
            int ch = i * 256 + tid;
            __builtin_amdgcn_global_load_lds((GAS*)(Kb_b + (long)kt * 16384 + koff[i]),
                                             (LAS*)(lds + LDS_K + ch * 16), 16, 0, 0);
            __builtin_amdgcn_global_load_lds((GAS*)(Vb_b + (long)kt * 128 + voff[i]),
                                             (LAS*)(lds + LDS_V + ch * 16), 16, 0, 0);
        }
        __syncthreads();   // vmcnt(0) drain + barrier: tile resident

        // ---- S^T = K Q^T : lane (l16,g) gets S[k=ct*16+g*4+r][q=w*16+l16] ----
        f32x4 s[4];
        __builtin_amdgcn_s_setprio(1);
        #pragma unroll
        for (int ct = 0; ct < 4; ++ct) {
            s[ct] = (f32x4){0.f, 0.f, 0.f, 0.f};
            #pragma unroll
            for (int kb = 0; kb < 4; ++kb) {
                short8 kf = *reinterpret_cast<const short8*>(kaddr[kb] + ct * 4096);
                s[ct] = __builtin_amdgcn_mfma_f32_16x16x32_bf16(kf, qf[kb], s[ct], 0, 0, 0);
            }
        }
        __builtin_amdgcn_s_setprio(0);

        // ---- causal mask: only diagonal tile (wave-uniform branch) ----
        if (kt == qt) {
            #pragma unroll
            for (int ct = 0; ct < 4; ++ct) {
                const int kg = kt * 64 + ct * 16 + g * 4;
                #pragma unroll
                for (int r = 0; r < 4; ++r)
                    if (kg + r > myq) s[ct][r] = -1e30f;
            }
        }

        // ---- online softmax (log2 domain), scalar m/lsum, defer-rescale (T13) ----
        float rmax = s[0][0];
        #pragma unroll
        for (int ct = 0; ct < 4; ++ct) {
            #pragma unroll
            for (int r = 0; r < 4; ++r) rmax = fmaxf(rmax, s[ct][r]);
        }
        rmax = fmaxf(rmax, __shfl_xor(rmax, 16, 64));
        rmax = fmaxf(rmax, __shfl_xor(rmax, 32, 64));
        if (__any(rmax > m + 11.5f)) {      // 2^11.5 ~ e^8 headroom
            float mn = fmaxf(m, rmax);
            float al = exp2f(m - mn);
            m = mn;
            lsum *= al;
            #pragma unroll
            for (int dt = 0; dt < 8; ++dt) {
                #pragma unroll
                for (int r = 0; r < 4; ++r) o[dt][r] *= al;
            }
        }
        float rsum = 0.f;
        #pragma unroll
        for (int ct = 0; ct < 4; ++ct) {
            #pragma unroll
            for (int r = 0; r < 4; ++r) {
                float p = exp2f(s[ct][r] - m);
                s[ct][r] = p;
                rsum += p;
            }
        }
        rsum += __shfl_xor(rsum, 16, 64);
        rsum += __shfl_xor(rsum, 32, 64);
        lsum += rsum;

        // ---- P -> per-wave LDS: cvt_pk pairs, 4x ds_write_b64 (k consecutive per lane) ----
        #pragma unroll
        for (int ct = 0; ct < 4; ++ct) {
            uint2v pb;
            pb[0] = cvt_pk_bf16(s[ct][0], s[ct][1]);
            pb[1] = cvt_pk_bf16(s[ct][2], s[ct][3]);
            *reinterpret_cast<uint2v*>(pwrite[ct]) = pb;
        }

        // ---- O += P V (proven r8 path: 16x16x32, P as A-frag, V as B-frag) ----
        #pragma unroll
        for (int kvb = 0; kvb < 2; ++kvb) {
            short8 pf = *reinterpret_cast<const short8*>(pread[kvb]);
            __builtin_amdgcn_s_setprio(1);
            #pragma unroll
            for (int dt = 0; dt < 8; ++dt) {
                short8 vf = *reinterpret_cast<const short8*>(vaddr[kvb] + dt * 2048);
                o[dt] = __builtin_amdgcn_mfma_f32_16x16x32_bf16(pf, vf, o[dt], 0, 0, 0);
            }
            __builtin_amdgcn_s_setprio(0);
        }

        if (kt < ktend) __syncthreads();   // all waves done with tile before next DMA
    }

    // ---- partial epilogue (r8 layout): o[dt][r] = O[q = w*16+g*4+r][d = dt*16+l16] ----
    unsigned short* Op = Opart + (long)slot * 8192;
    #pragma unroll
    for (int dt = 0; dt < 8; ++dt) {
        #pragma unroll
        for (int r = 0; r < 4; ++r) {
            Op[(w * 16 + g * 4 + r) * 128 + dt * 16 + l16] = f2bf(o[dt][r]);
        }
    }
    if (g == 0) {   // m/lsum are per-lane (q-row = w*16 + l16), quad-consistent
        Mpart[(long)slot * 64 + w * 16 + l16] = m;
        Lpart[(long)slot * 64 + w * 16 + l16] = lsum;
    }
}

// ---------------- kernel 3: combine partials (m in log2 domain -> exp2) ----------------
// grid (256, 4): x = qt*4 + quarter, y = b. Each block merges 16 rows of one q-tile.
__global__ __launch_bounds__(256) void combine_kernel(const unsigned short* __restrict__ Opart,
                                                      const float* __restrict__ Mpart,
                                                      const float* __restrict__ Lpart,
                                                      float* __restrict__ out) {
    __shared__ float coeff[16][16];
    __shared__ float invL[16];

    const int qt = blockIdx.x >> 2, qq = blockIdx.x & 3, b = blockIdx.y;
    const int gg = qt >> 2;
    const int nc = gg + 1;
    const int slot0 = b * CPB + 2 * gg * (gg + 1) + (qt - 4 * gg) * nc;
    const int r0 = qq * 16;

    const int tid = threadIdx.x;
    if (tid < 16) {
        float mg = -INFINITY;
        for (int c = 0; c < nc; ++c)
            mg = fmaxf(mg, Mpart[(long)(slot0 + c) * 64 + r0 + tid]);
        float L = 0.f;
        for (int c = 0; c < nc; ++c) {
            float co = exp2f(Mpart[(long)(slot0 + c) * 64 + r0 + tid] - mg);
            coeff[c][tid] = co;
            L += co * Lpart[(long)(slot0 + c) * 64 + r0 + tid];
        }
        invL[tid] = 1.f / L;
    }
    __syncthreads();

    const int e0 = tid * 8;
    const int r = e0 >> 7;
    float acc[8];
    #pragma unroll
    for (int k = 0; k < 8; ++k) acc[k] = 0.f;
    for (int c = 0; c < nc; ++c) {
        short8 v = *reinterpret_cast<const short8*>(Opart + (long)(slot0 + c) * 8192 + r0 * 128 + e0);
        const float co = coeff[c][r];
        #pragma unroll
        for (int k = 0; k < 8; ++k)
            acc[k] += co * bf2f((unsigned short)v[k]);
    }
    const float s = invL[r];
    float4v o0, o1;
    o0[0] = acc[0] * s; o0[1] = acc[1] * s; o0[2] = acc[2] * s; o0[3] = acc[3] * s;
    o1[0] = acc[4] * s; o1[1] = acc[5] * s; o1[2] = acc[6] * s; o1[3] = acc[7] * s;
    float* dst = out + ((long)b * S_ + qt * 64 + r0) * 128 + e0;
    *reinterpret_cast<float4v*>(dst) = o0;
    *reinterpret_cast<float4v*>(dst + 4) = o1;
}

extern "C" void kernel_launch(void* const* d_in, const int* in_sizes, int n_in,
                              void* d_out, int out_size, void* d_ws, size_t ws_size,
                              hipStream_t stream) {
    (void)in_sizes; (void)n_in; (void)out_size; (void)ws_size;
    const float* x  = (const float*)d_in[0];
    const float* Wq = (const float*)d_in[1];
    const float* Wk = (const float*)d_in[2];
    const float* Wv = (const float*)d_in[3];
    float* out = (float*)d_out;

    char* ws = (char*)d_ws;
    const size_t MB4 = (size_t)16384 * 128 * 2;         // 4 MiB per bf16 tensor
    unsigned short* Qb = (unsigned short*)(ws);
    unsigned short* Kb = (unsigned short*)(ws + MB4);
    unsigned short* Vt = (unsigned short*)(ws + 2 * MB4);
    unsigned short* Wb = (unsigned short*)(ws + 3 * MB4);          // 96 KiB
    unsigned short* Opart = (unsigned short*)(ws + 3 * MB4 + (1 << 20));   // 2176*16KiB
    float* Mpart = (float*)(ws + 3 * MB4 + (1 << 20) + (size_t)NSLOT * 8192 * 2);
    float* Lpart = Mpart + (size_t)NSLOT * 64;

    wconv_kernel<<<192, 256, 0, stream>>>(Wq, Wk, Wv, Wb);
    qkv_kernel<<<dim3(256, 3), 256, 0, stream>>>(x, Wb, Qb, Kb, Vt);
    attn_kernel<<<NSLOT, 256, 0, stream>>>(Qb, Kb, Vt, Opart, Mpart, Lpart);
    combine_kernel<<<dim3(256, 4), 256, 0, stream>>>(Opart, Mpart, Lpart, out);
}